// Round 10
// baseline (667.754 us; speedup 1.0000x reference)
//
#include <hip/hip_runtime.h>

#define EPSF 1e-6f
#define LN2F 0.69314718055994531f

typedef _Float16 half8 __attribute__((ext_vector_type(8)));
typedef float f32x4 __attribute__((ext_vector_type(4)));

constexpr int B = 128, L = 512, S = 512, C = 64;
constexpr int TILE_R = 64;            // rows per pass-1 block
constexpr int TILES  = L / TILE_R;    // 8
constexpr int CHUNK  = 64;            // cols per k-chunk
constexpr int NCHUNK = S / CHUNK;     // 8
constexpr int HALVES = 2;             // S-split: each block does NCHUNK/HALVES chunks
constexpr int CPB    = NCHUNK / HALVES;   // 4 chunks per block
constexpr int BPB    = TILES * HALVES;    // 16 pass-1 blocks per batch b

// workspace float offsets (row stats are per-half partials)
constexpr size_t WS_COLMAX = 0;
constexpr size_t WS_COLSUM = WS_COLMAX + (size_t)B * TILES * S;
constexpr size_t WS_COLSSQ = WS_COLSUM + (size_t)B * TILES * S;
constexpr size_t WS_COLP1  = WS_COLSSQ + (size_t)B * TILES * S;
constexpr size_t WS_ROWMAX = WS_COLP1  + (size_t)B * TILES * S;
constexpr size_t WS_ROWSUM = WS_ROWMAX + (size_t)B * L * HALVES;
constexpr size_t WS_ROWSSQ = WS_ROWSUM + (size_t)B * L * HALVES;
constexpr size_t WS_ROWP2  = WS_ROWSSQ + (size_t)B * L * HALVES;
constexpr size_t WS_NEGS   = WS_ROWP2  + (size_t)B * L * HALVES;
constexpr size_t WS_NEGC   = WS_NEGS   + (size_t)B * TILES * HALVES;
// fused-finish bookkeeping (zeroed by a 520B memset before launch):
// [0..127] per-b arrival counters (int), [128] global finisher counter (int),
// [129] scalar loss accumulator (float)
constexpr size_t WS_CNT    = WS_NEGC   + (size_t)B * TILES * HALVES;

// Load a thread's 16 consecutive floats of a 64x64 tile: row = t>>2, c0 = (t&3)*16.
__device__ inline void loadTile(const float* __restrict__ g, float4 v[4], int t)
{
    const float* src = g + (t >> 2) * 64 + (t & 3) * 16;
    v[0] = *(const float4*)(src);
    v[1] = *(const float4*)(src + 4);
    v[2] = *(const float4*)(src + 8);
    v[3] = *(const float4*)(src + 12);
}

// Write regs into frag-swizzled fp16 hi/lo LDS (exact R7 layout — R9 proved the
// bank swizzle eliminates the 3.9M conflicts but buys 0 time (hidden under
// latency) and its +2 VGPR nudged mild spill; reverted).
__device__ inline void stageW(const float4 v4[4], half8 (*hiA)[64], half8 (*loA)[64], int t)
{
    const int row = t >> 2, c0 = (t & 3) * 16;
    const float v[16] = {v4[0].x, v4[0].y, v4[0].z, v4[0].w, v4[1].x, v4[1].y, v4[1].z, v4[1].w,
                         v4[2].x, v4[2].y, v4[2].z, v4[2].w, v4[3].x, v4[3].y, v4[3].z, v4[3].w};
#pragma unroll
    for (int o = 0; o < 2; ++o) {
        const int cb     = c0 + o * 8;
        const int idx    = (row >> 4) * 2 + (cb >> 5);
        const int lane_s = (((cb >> 3) & 3) << 4) + (row & 15);
        half8 h, l;
#pragma unroll
        for (int j = 0; j < 8; ++j) {
            float f = v[o * 8 + j];
            _Float16 hi = (_Float16)f;
            h[j] = hi;
            l[j] = (_Float16)(f - (float)hi);
        }
        hiA[idx][lane_s] = h;
        loA[idx][lane_s] = l;
    }
}

// block reduce over 256 threads (4 waves); red needs >= 5 floats
template <bool MAX>
__device__ inline float bred4(float v, float* red)
{
#pragma unroll
    for (int m = 1; m <= 32; m <<= 1) {
        float o = __shfl_xor(v, m, 64);
        v = MAX ? fmaxf(v, o) : (v + o);
    }
    const int wave = threadIdx.x >> 6;
    if ((threadIdx.x & 63) == 0) red[wave] = v;
    __syncthreads();
    if (threadIdx.x == 0) {
        float r = red[0];
        for (int w = 1; w < 4; ++w) r = MAX ? fmaxf(r, red[w]) : (r + red[w]);
        red[4] = r;
    }
    __syncthreads();
    float out = red[4];
    __syncthreads();
    return out;
}

// R10: R7 structure (best measured, VGPR 84, no spill) + FUSED pass2.
// Last-block-per-b pattern (rocPRIM-style): after this block's ws writes,
// release fence + atomicAdd(cnt[b]); the 16th arrival acquires and runs the
// whole of b's pass2 (col softmax+loss1, row softmax+loss2+loss3) with 256
// threads x 2 elements, OVERLAPPED with other batches' pass1. A global counter
// designates the last finisher, which writes the final scalar loss (plain
// overwrite -> no d_out pre-zeroing needed). Kills the pass2 dispatch + gap.
__global__ __launch_bounds__(256) __attribute__((amdgpu_waves_per_eu(3, 8)))
void pass1_kernel(const float* __restrict__ q, const float* __restrict__ kmat,
                  const int* __restrict__ labels, float* __restrict__ ws,
                  float* __restrict__ outp)
{
    __shared__ half8 khiF[8][64], kloF[8][64];   // 16 KB: frag-swizzled k (q in prologue)
    __shared__ float4 colred4[4][CHUNK];         // 4 KB (shuffle-reduced partials)
    __shared__ float nred[4][2];
    __shared__ float fred[5];                    // finisher block-reduce scratch
    __shared__ int   finflag;

    const int bidx = blockIdx.x;
    const int b    = bidx / BPB;
    const int rem  = bidx % BPB;
    const int tile = rem >> 1;
    const int half = rem & 1;
    const int chbase = half * CPB;
    const int tid  = threadIdx.x;
    const int lane = tid & 63;
    const int wave = tid >> 6;
    const int l15  = lane & 15;
    const int quad = lane >> 4;
    const int rowbase = tile * TILE_R;

    float* colmax_p = ws + WS_COLMAX;
    float* colsum_p = ws + WS_COLSUM;
    float* colssq_p = ws + WS_COLSSQ;
    float* colp1_p  = ws + WS_COLP1;
    float* rowmax_p = ws + WS_ROWMAX;
    float* rowsum_p = ws + WS_ROWSUM;
    float* rowssq_p = ws + WS_ROWSSQ;
    float* rowp2_p  = ws + WS_ROWP2;
    float* negs_p   = ws + WS_NEGS;
    float* negc_p   = ws + WS_NEGC;
    int*   cnt_p    = (int*)(ws + WS_CNT);       // [0..127] per-b, [128] global
    float* acc_p    = ws + WS_CNT + 129;         // scalar loss accumulator

    const float* kb = kmat + (size_t)b * S * C;
    const int*   lb = labels + ((size_t)b * L + rowbase) * S;

    // --- prologue: q -> frag-swizzled LDS -> A fragments in registers ---
    float4 tv[4];
    loadTile(q + ((size_t)b * L + rowbase) * C, tv, tid);
    stageW(tv, khiF, kloF, tid);
    // labels for first chunk (consumed in first epilogue; reloaded after each)
    int labn[16];
#pragma unroll
    for (int ct = 0; ct < 4; ++ct)
#pragma unroll
        for (int r = 0; r < 4; ++r)
            labn[ct * 4 + r] = __builtin_nontemporal_load(
                &lb[(size_t)(wave * 16 + quad * 4 + r) * S
                    + chbase * CHUNK + ct * 16 + l15]);
    __syncthreads();   // publish q staging before fragment reads
    half8 ah0 = khiF[wave * 2 + 0][lane], ah1 = khiF[wave * 2 + 1][lane];
    half8 al0 = kloF[wave * 2 + 0][lane], al1 = kloF[wave * 2 + 1][lane];
    // prefetch first k chunk into registers (khiF not overwritten until after S1)
    loadTile(kb + (size_t)chbase * CHUNK * C, tv, tid);

    float rmax[4], rsum[4], rssq[4], rp2[4];
#pragma unroll
    for (int i = 0; i < 4; ++i) { rmax[i] = -3.4e38f; rsum[i] = 0.f; rssq[i] = 0.f; rp2[i] = 0.f; }
    float nlsum = 0.f;   // sum of log2(t) over ALL elements (negative)
    int   possum = 0;

    for (int c4 = 0; c4 < CPB; ++c4) {
        const int ch = chbase + c4;
        __syncthreads();   // S1: prev chunk's khiF frag reads + colred writes complete
        // combine + store column partials of previous chunk (reads colred4)
        if (c4 > 0 && tid < CHUNK) {
            float4 v = colred4[0][tid];
            float m0 = v.x, s1 = v.y, s2 = v.z, pp = v.w;
#pragma unroll
            for (int w = 1; w < 4; ++w) {
                float4 u = colred4[w][tid];
                m0 = fmaxf(m0, u.x); s1 += u.y; s2 += u.z; pp += u.w;
            }
            size_t idx = ((size_t)b * TILES + tile) * S + (ch - 1) * CHUNK + tid;
            colmax_p[idx] = m0; colsum_p[idx] = s1; colssq_p[idx] = s2; colp1_p[idx] = pp;
        }
        stageW(tv, khiF, kloF, tid);           // convert + write k(ch)
        if (c4 + 1 < CPB)
            loadTile(kb + (size_t)(ch + 1) * CHUNK * C, tv, tid);   // prefetch k(ch+1)
        __syncthreads();   // S2: k(ch) visible; colred4 reads done before re-write

        f32x4 acc[4];
#pragma unroll
        for (int ct = 0; ct < 4; ++ct) {
            half8 bh0 = khiF[ct * 2 + 0][lane], bh1 = khiF[ct * 2 + 1][lane];
            half8 bl0 = kloF[ct * 2 + 0][lane], bl1 = kloF[ct * 2 + 1][lane];
            f32x4 a = {0.f, 0.f, 0.f, 0.f};
            a = __builtin_amdgcn_mfma_f32_16x16x32_f16(ah0, bh0, a, 0, 0, 0);
            a = __builtin_amdgcn_mfma_f32_16x16x32_f16(ah0, bl0, a, 0, 0, 0);
            a = __builtin_amdgcn_mfma_f32_16x16x32_f16(al0, bh0, a, 0, 0, 0);
            a = __builtin_amdgcn_mfma_f32_16x16x32_f16(ah1, bh1, a, 0, 0, 0);
            a = __builtin_amdgcn_mfma_f32_16x16x32_f16(ah1, bl1, a, 0, 0, 0);
            a = __builtin_amdgcn_mfma_f32_16x16x32_f16(al1, bh1, a, 0, 0, 0);
            acc[ct] = a;
        }

        // epilogue: C/D layout col = l15, row = quad*4 + r  [m89-verified]
        // log2-domain NLL: accumulate raw log2, scale by -ln2 once at the end.
#pragma unroll
        for (int ct = 0; ct < 4; ++ct) {
            float cmax = -3.4e38f, csum = 0.f, cssq = 0.f, cp1 = 0.f;
#pragma unroll
            for (int r = 0; r < 4; ++r) {
                int lab = labn[ct * 4 + r];
                float sim = fmaf(0.5f, acc[ct][r], 0.5f);
                rmax[r] = fmaxf(rmax[r], sim);
                rsum[r] += sim;
                rssq[r] = fmaf(sim, sim, rssq[r]);
                cmax = fmaxf(cmax, sim);
                csum += sim;
                cssq = fmaf(sim, sim, cssq);
                bool  isp = (lab == 1);
                float tt  = isp ? sim : (1.f - sim);
                tt = fminf(fmaxf(tt, EPSF), 1.f - EPSF);
                float l2 = __log2f(tt);          // negative
                float pv = isp ? l2 : 0.f;
                rp2[r] += pv;                    // log2-domain pos-NLL
                cp1   += pv;
                nlsum += l2;                     // all elements
                possum += lab;
            }
            cp1 *= -LN2F;                        // natural-log positive NLL
            // column reduce across quads (lanes sharing l15): xor 16, 32
#pragma unroll
            for (int m = 16; m <= 32; m <<= 1) {
                cmax = fmaxf(cmax, __shfl_xor(cmax, m, 64));
                csum += __shfl_xor(csum, m, 64);
                cssq += __shfl_xor(cssq, m, 64);
                cp1  += __shfl_xor(cp1,  m, 64);
            }
            if (lane < 16)
                colred4[wave][ct * 16 + l15] = make_float4(cmax, csum, cssq, cp1);
        }

        // prefetch next chunk's labels AFTER consumption (cover: next S1/S2 +
        // staging + MFMA of chunk ch+1)
        if (c4 + 1 < CPB) {
#pragma unroll
            for (int ct = 0; ct < 4; ++ct)
#pragma unroll
                for (int r = 0; r < 4; ++r)
                    labn[ct * 4 + r] = __builtin_nontemporal_load(
                        &lb[(size_t)(wave * 16 + quad * 4 + r) * S
                            + (ch + 1) * CHUNK + ct * 16 + l15]);
        }
    }

    __syncthreads();
    if (tid < CHUNK) {   // last chunk's column partials
        float4 v = colred4[0][tid];
        float m0 = v.x, s1 = v.y, s2 = v.z, pp = v.w;
#pragma unroll
        for (int w = 1; w < 4; ++w) {
            float4 u = colred4[w][tid];
            m0 = fmaxf(m0, u.x); s1 += u.y; s2 += u.z; pp += u.w;
        }
        size_t idx = ((size_t)b * TILES + tile) * S + (chbase + CPB - 1) * CHUNK + tid;
        colmax_p[idx] = m0; colsum_p[idx] = s1; colssq_p[idx] = s2; colp1_p[idx] = pp;
    }

    // scale pos-NLL accumulators to natural log; derive this thread's negsum
#pragma unroll
    for (int r = 0; r < 4; ++r) rp2[r] *= -LN2F;
    float negsum = fmaf(-LN2F, nlsum, -(rp2[0] + rp2[1] + rp2[2] + rp2[3]));

    // row reduce across l15 (lanes sharing quad): xor 1,2,4,8 -> per-half partial
#pragma unroll
    for (int r = 0; r < 4; ++r) {
#pragma unroll
        for (int m = 1; m <= 8; m <<= 1) {
            rmax[r] = fmaxf(rmax[r], __shfl_xor(rmax[r], m, 64));
            rsum[r] += __shfl_xor(rsum[r], m, 64);
            rssq[r] += __shfl_xor(rssq[r], m, 64);
            rp2[r]  += __shfl_xor(rp2[r],  m, 64);
        }
    }
    if (l15 == 0) {
#pragma unroll
        for (int r = 0; r < 4; ++r) {
            size_t idx = ((size_t)b * L + rowbase + wave * 16 + quad * 4 + r) * HALVES + half;
            rowmax_p[idx] = rmax[r]; rowsum_p[idx] = rsum[r];
            rowssq_p[idx] = rssq[r]; rowp2_p[idx]  = rp2[r];
        }
    }

    // negatives: full block reduce (negcnt = elements - possum)
    float negcnt = (float)(16 * CPB - possum);
#pragma unroll
    for (int m = 1; m <= 32; m <<= 1) {
        negsum += __shfl_xor(negsum, m, 64);
        negcnt += __shfl_xor(negcnt, m, 64);
    }
    if (lane == 0) { nred[wave][0] = negsum; nred[wave][1] = negcnt; }
    __syncthreads();
    if (tid == 0) {
        float ns = 0.f, nc = 0.f;
        for (int w = 0; w < 4; ++w) { ns += nred[w][0]; nc += nred[w][1]; }
        negs_p[bidx] = ns; negc_p[bidx] = nc;
    }

    // ---- fused finish: last block of this b runs pass2 for b ----
    __syncthreads();      // all this block's ws stores issued (vmcnt drained)
    __threadfence();      // release: make them visible device-wide (L2 wb)
    if (tid == 0) {
        int old = atomicAdd(&cnt_p[b], 1);
        finflag = (old == BPB - 1);
    }
    __syncthreads();
    if (!finflag) return;
    __threadfence();      // acquire: invalidate stale caches before reading

    // ===== column path: softmax over S scores + loss1 (2 cols/thread) =====
    float score[2], p1v[2];
#pragma unroll
    for (int j = 0; j < 2; ++j) {
        const int s = tid + j * 256;
        float m = -3.4e38f, sm = 0.f, sq = 0.f, pp = 0.f;
#pragma unroll
        for (int t = 0; t < TILES; ++t) {
            size_t idx = ((size_t)b * TILES + t) * S + s;
            m = fmaxf(m, colmax_p[idx]);
            sm += colsum_p[idx];
            sq += colssq_p[idx];
            pp += colp1_p[idx];
        }
        float mean = sm * (1.f / L);
        float var  = (sq - sm * sm * (1.f / L)) * (1.f / (L - 1));
        score[j] = (m - mean) / sqrtf(var);
        p1v[j]   = pp;
    }
    float gmax = bred4<true>(fmaxf(score[0], score[1]), fred);
    float e0 = __expf(score[0] - gmax), e1 = __expf(score[1] - gmax);
    float esum = bred4<false>(e0 + e1, fred);
    float inv = 1.f / esum;
    outp[(size_t)b * S + tid]       = e0 * inv;
    outp[(size_t)b * S + tid + 256] = e1 * inv;
    float loss1 = bred4<false>(e0 * inv * p1v[0] + e1 * inv * p1v[1], fred);

    // ===== row path: softmax over L scores + loss2 (2 rows/thread) =====
    float score2[2], p2v[2];
#pragma unroll
    for (int j = 0; j < 2; ++j) {
        const int row = tid + j * 256;
        size_t ridx = ((size_t)b * L + row) * HALVES;
        float m2  = fmaxf(rowmax_p[ridx], rowmax_p[ridx + 1]);
        float sm2 = rowsum_p[ridx] + rowsum_p[ridx + 1];
        float sq2 = rowssq_p[ridx] + rowssq_p[ridx + 1];
        float p2  = rowp2_p[ridx]  + rowp2_p[ridx + 1];
        float mean2 = sm2 * (1.f / S);
        float var2  = (sq2 - sm2 * sm2 * (1.f / S)) * (1.f / (S - 1));
        score2[j] = (m2 - mean2) / sqrtf(var2);
        p2v[j]    = p2;
    }
    float gmax2 = bred4<true>(fmaxf(score2[0], score2[1]), fred);
    float f0 = __expf(score2[0] - gmax2), f1 = __expf(score2[1] - gmax2);
    float esum2 = bred4<false>(f0 + f1, fred);
    float inv2 = 1.f / esum2;
    float loss2 = bred4<false>(f0 * inv2 * p2v[0] + f1 * inv2 * p2v[1], fred);

    if (tid == 0) {
        float ns = 0.f, nc = 0.f;
        for (int t = 0; t < BPB; ++t) {
            ns += negs_p[b * BPB + t];
            nc += negc_p[b * BPB + t];
        }
        float lb_total = (0.5f * (loss1 + loss2) + ns / nc) * (1.f / B);
        atomicAdd(acc_p, lb_total);
        __threadfence();
        int old2 = atomicAdd(&cnt_p[B], 1);
        if (old2 == B - 1)
            outp[(size_t)B * S] = atomicAdd(acc_p, 0.f);   // atomic read of total
    }
}

extern "C" void kernel_launch(void* const* d_in, const int* in_sizes, int n_in,
                              void* d_out, int out_size, void* d_ws, size_t ws_size,
                              hipStream_t stream)
{
    const float* q      = (const float*)d_in[0];
    const float* k      = (const float*)d_in[1];
    const int*   labels = (const int*)d_in[2];
    float* out = (float*)d_out;
    float* ws  = (float*)d_ws;

    // zero the fused-finish bookkeeping (128 per-b counters + global counter +
    // scalar accumulator = 520 B); workspace is poisoned before each replay
    hipMemsetAsync(ws + WS_CNT, 0, 130 * sizeof(float), stream);

    pass1_kernel<<<dim3(B * TILES * HALVES), dim3(256), 0, stream>>>(q, k, labels, ws, out);
}

// Round 11
// 249.014 us; speedup vs baseline: 2.6816x; 2.6816x over previous
//
#include <hip/hip_runtime.h>

#define EPSF 1e-6f
#define LN2F 0.69314718055994531f

typedef _Float16 half8 __attribute__((ext_vector_type(8)));
typedef float f32x4 __attribute__((ext_vector_type(4)));

constexpr int B = 128, L = 512, S = 512, C = 64;
constexpr int TILE_R = 64;            // rows per pass-1 block
constexpr int TILES  = L / TILE_R;    // 8
constexpr int CHUNK  = 64;            // cols per k-chunk
constexpr int NCHUNK = S / CHUNK;     // 8 chunks, ALL done by one block (R11: HALVES=1)
constexpr int CPB    = NCHUNK;        // 8 chunks per block

// workspace float offsets (row stats now full-row, no half split)
constexpr size_t WS_COLMAX = 0;
constexpr size_t WS_COLSUM = WS_COLMAX + (size_t)B * TILES * S;
constexpr size_t WS_COLSSQ = WS_COLSUM + (size_t)B * TILES * S;
constexpr size_t WS_COLP1  = WS_COLSSQ + (size_t)B * TILES * S;
constexpr size_t WS_ROWMAX = WS_COLP1  + (size_t)B * TILES * S;
constexpr size_t WS_ROWSUM = WS_ROWMAX + (size_t)B * L;
constexpr size_t WS_ROWSSQ = WS_ROWSUM + (size_t)B * L;
constexpr size_t WS_ROWP2  = WS_ROWSSQ + (size_t)B * L;
constexpr size_t WS_NEGS   = WS_ROWP2  + (size_t)B * L;
constexpr size_t WS_NEGC   = WS_NEGS   + (size_t)B * TILES;

// Load a thread's 16 consecutive floats of a 64x64 tile: row = t>>2, c0 = (t&3)*16.
__device__ inline void loadTile(const float* __restrict__ g, float4 v[4], int t)
{
    const float* src = g + (t >> 2) * 64 + (t & 3) * 16;
    v[0] = *(const float4*)(src);
    v[1] = *(const float4*)(src + 4);
    v[2] = *(const float4*)(src + 8);
    v[3] = *(const float4*)(src + 12);
}

// Write regs into frag-swizzled fp16 hi/lo LDS (exact R7 layout — R9 proved the
// bank swizzle removes the 3.9M conflict cycles but buys 0 time: hidden under
// latency; R10 proved per-block device fences cost 7x. Both reverted.)
__device__ inline void stageW(const float4 v4[4], half8 (*hiA)[64], half8 (*loA)[64], int t)
{
    const int row = t >> 2, c0 = (t & 3) * 16;
    const float v[16] = {v4[0].x, v4[0].y, v4[0].z, v4[0].w, v4[1].x, v4[1].y, v4[1].z, v4[1].w,
                         v4[2].x, v4[2].y, v4[2].z, v4[2].w, v4[3].x, v4[3].y, v4[3].z, v4[3].w};
#pragma unroll
    for (int o = 0; o < 2; ++o) {
        const int cb     = c0 + o * 8;
        const int idx    = (row >> 4) * 2 + (cb >> 5);
        const int lane_s = (((cb >> 3) & 3) << 4) + (row & 15);
        half8 h, l;
#pragma unroll
        for (int j = 0; j < 8; ++j) {
            float f = v[o * 8 + j];
            _Float16 hi = (_Float16)f;
            h[j] = hi;
            l[j] = (_Float16)(f - (float)hi);
        }
        hiA[idx][lane_s] = h;
        loA[idx][lane_s] = l;
    }
}

// R11 = R7 champion (236.5us) with HALVES=1: 1024 blocks x 8 chunks.
// Mechanism: per-block prologue (q stage + first k prefetch + first labels)
// amortizes over 8 chunks not 4; q staged once per tile not twice; row-stat
// traffic halves; pass2 half-combine disappears. Same inner loop, same LDS,
// chbase is now constant 0 (fewer address registers, not more).
__global__ __launch_bounds__(256) __attribute__((amdgpu_waves_per_eu(3, 8)))
void pass1_kernel(const float* __restrict__ q, const float* __restrict__ kmat,
                  const int* __restrict__ labels, float* __restrict__ ws,
                  float* __restrict__ outp)
{
    __shared__ half8 khiF[8][64], kloF[8][64];   // 16 KB: frag-swizzled k (q in prologue)
    __shared__ float4 colred4[4][CHUNK];         // 4 KB (shuffle-reduced partials)
    __shared__ float nred[4][2];

    const int bidx = blockIdx.x;
    const int b    = bidx / TILES;
    const int tile = bidx % TILES;
    const int tid  = threadIdx.x;
    const int lane = tid & 63;
    const int wave = tid >> 6;
    const int l15  = lane & 15;
    const int quad = lane >> 4;
    const int rowbase = tile * TILE_R;

    if (bidx == 0 && tid == 0) outp[(size_t)B * S] = 0.f;   // replaces memset dispatch

    float* colmax_p = ws + WS_COLMAX;
    float* colsum_p = ws + WS_COLSUM;
    float* colssq_p = ws + WS_COLSSQ;
    float* colp1_p  = ws + WS_COLP1;
    float* rowmax_p = ws + WS_ROWMAX;
    float* rowsum_p = ws + WS_ROWSUM;
    float* rowssq_p = ws + WS_ROWSSQ;
    float* rowp2_p  = ws + WS_ROWP2;
    float* negs_p   = ws + WS_NEGS;
    float* negc_p   = ws + WS_NEGC;

    const float* kb = kmat + (size_t)b * S * C;
    const int*   lb = labels + ((size_t)b * L + rowbase) * S;

    // --- prologue: q -> frag-swizzled LDS -> A fragments in registers ---
    float4 tv[4];
    loadTile(q + ((size_t)b * L + rowbase) * C, tv, tid);
    stageW(tv, khiF, kloF, tid);
    // labels for first chunk (consumed in first epilogue; reloaded after each)
    int labn[16];
#pragma unroll
    for (int ct = 0; ct < 4; ++ct)
#pragma unroll
        for (int r = 0; r < 4; ++r)
            labn[ct * 4 + r] = __builtin_nontemporal_load(
                &lb[(size_t)(wave * 16 + quad * 4 + r) * S + ct * 16 + l15]);
    __syncthreads();   // publish q staging before fragment reads
    half8 ah0 = khiF[wave * 2 + 0][lane], ah1 = khiF[wave * 2 + 1][lane];
    half8 al0 = kloF[wave * 2 + 0][lane], al1 = kloF[wave * 2 + 1][lane];
    // prefetch first k chunk into registers (khiF not overwritten until after S1)
    loadTile(kb, tv, tid);

    float rmax[4], rsum[4], rssq[4], rp2[4];
#pragma unroll
    for (int i = 0; i < 4; ++i) { rmax[i] = -3.4e38f; rsum[i] = 0.f; rssq[i] = 0.f; rp2[i] = 0.f; }
    float nlsum = 0.f;   // sum of log2(t) over ALL elements (negative)
    int   possum = 0;

    for (int c4 = 0; c4 < CPB; ++c4) {
        __syncthreads();   // S1: prev chunk's khiF frag reads + colred writes complete
        // combine + store column partials of previous chunk (reads colred4)
        if (c4 > 0 && tid < CHUNK) {
            float4 v = colred4[0][tid];
            float m0 = v.x, s1 = v.y, s2 = v.z, pp = v.w;
#pragma unroll
            for (int w = 1; w < 4; ++w) {
                float4 u = colred4[w][tid];
                m0 = fmaxf(m0, u.x); s1 += u.y; s2 += u.z; pp += u.w;
            }
            size_t idx = ((size_t)b * TILES + tile) * S + (c4 - 1) * CHUNK + tid;
            colmax_p[idx] = m0; colsum_p[idx] = s1; colssq_p[idx] = s2; colp1_p[idx] = pp;
        }
        stageW(tv, khiF, kloF, tid);           // convert + write k(c4)
        if (c4 + 1 < CPB)
            loadTile(kb + (size_t)(c4 + 1) * CHUNK * C, tv, tid);   // prefetch k(c4+1)
        __syncthreads();   // S2: k(c4) visible; colred4 reads done before re-write

        f32x4 acc[4];
#pragma unroll
        for (int ct = 0; ct < 4; ++ct) {
            half8 bh0 = khiF[ct * 2 + 0][lane], bh1 = khiF[ct * 2 + 1][lane];
            half8 bl0 = kloF[ct * 2 + 0][lane], bl1 = kloF[ct * 2 + 1][lane];
            f32x4 a = {0.f, 0.f, 0.f, 0.f};
            a = __builtin_amdgcn_mfma_f32_16x16x32_f16(ah0, bh0, a, 0, 0, 0);
            a = __builtin_amdgcn_mfma_f32_16x16x32_f16(ah0, bl0, a, 0, 0, 0);
            a = __builtin_amdgcn_mfma_f32_16x16x32_f16(al0, bh0, a, 0, 0, 0);
            a = __builtin_amdgcn_mfma_f32_16x16x32_f16(ah1, bh1, a, 0, 0, 0);
            a = __builtin_amdgcn_mfma_f32_16x16x32_f16(ah1, bl1, a, 0, 0, 0);
            a = __builtin_amdgcn_mfma_f32_16x16x32_f16(al1, bh1, a, 0, 0, 0);
            acc[ct] = a;
        }

        // epilogue: C/D layout col = l15, row = quad*4 + r  [m89-verified]
        // log2-domain NLL: accumulate raw log2, scale by -ln2 once at the end.
#pragma unroll
        for (int ct = 0; ct < 4; ++ct) {
            float cmax = -3.4e38f, csum = 0.f, cssq = 0.f, cp1 = 0.f;
#pragma unroll
            for (int r = 0; r < 4; ++r) {
                int lab = labn[ct * 4 + r];
                float sim = fmaf(0.5f, acc[ct][r], 0.5f);
                rmax[r] = fmaxf(rmax[r], sim);
                rsum[r] += sim;
                rssq[r] = fmaf(sim, sim, rssq[r]);
                cmax = fmaxf(cmax, sim);
                csum += sim;
                cssq = fmaf(sim, sim, cssq);
                bool  isp = (lab == 1);
                float tt  = isp ? sim : (1.f - sim);
                tt = fminf(fmaxf(tt, EPSF), 1.f - EPSF);
                float l2 = __log2f(tt);          // negative
                float pv = isp ? l2 : 0.f;
                rp2[r] += pv;                    // log2-domain pos-NLL
                cp1   += pv;
                nlsum += l2;                     // all elements
                possum += lab;
            }
            cp1 *= -LN2F;                        // natural-log positive NLL
            // column reduce across quads (lanes sharing l15): xor 16, 32
#pragma unroll
            for (int m = 16; m <= 32; m <<= 1) {
                cmax = fmaxf(cmax, __shfl_xor(cmax, m, 64));
                csum += __shfl_xor(csum, m, 64);
                cssq += __shfl_xor(cssq, m, 64);
                cp1  += __shfl_xor(cp1,  m, 64);
            }
            if (lane < 16)
                colred4[wave][ct * 16 + l15] = make_float4(cmax, csum, cssq, cp1);
        }

        // prefetch next chunk's labels AFTER consumption (cover: next S1/S2 +
        // staging + MFMA of chunk c4+1)
        if (c4 + 1 < CPB) {
#pragma unroll
            for (int ct = 0; ct < 4; ++ct)
#pragma unroll
                for (int r = 0; r < 4; ++r)
                    labn[ct * 4 + r] = __builtin_nontemporal_load(
                        &lb[(size_t)(wave * 16 + quad * 4 + r) * S
                            + (c4 + 1) * CHUNK + ct * 16 + l15]);
        }
    }

    __syncthreads();
    if (tid < CHUNK) {   // last chunk's column partials
        float4 v = colred4[0][tid];
        float m0 = v.x, s1 = v.y, s2 = v.z, pp = v.w;
#pragma unroll
        for (int w = 1; w < 4; ++w) {
            float4 u = colred4[w][tid];
            m0 = fmaxf(m0, u.x); s1 += u.y; s2 += u.z; pp += u.w;
        }
        size_t idx = ((size_t)b * TILES + tile) * S + (CPB - 1) * CHUNK + tid;
        colmax_p[idx] = m0; colsum_p[idx] = s1; colssq_p[idx] = s2; colp1_p[idx] = pp;
    }

    // scale pos-NLL accumulators to natural log; derive this thread's negsum
    // BEFORE the row shuffles consume rp2
#pragma unroll
    for (int r = 0; r < 4; ++r) rp2[r] *= -LN2F;
    float negsum = fmaf(-LN2F, nlsum, -(rp2[0] + rp2[1] + rp2[2] + rp2[3]));

    // row reduce across l15 (lanes sharing quad): xor 1,2,4,8 -> FULL row stats
#pragma unroll
    for (int r = 0; r < 4; ++r) {
#pragma unroll
        for (int m = 1; m <= 8; m <<= 1) {
            rmax[r] = fmaxf(rmax[r], __shfl_xor(rmax[r], m, 64));
            rsum[r] += __shfl_xor(rsum[r], m, 64);
            rssq[r] += __shfl_xor(rssq[r], m, 64);
            rp2[r]  += __shfl_xor(rp2[r],  m, 64);
        }
    }
    if (l15 == 0) {
#pragma unroll
        for (int r = 0; r < 4; ++r) {
            size_t idx = (size_t)b * L + rowbase + wave * 16 + quad * 4 + r;
            rowmax_p[idx] = rmax[r]; rowsum_p[idx] = rsum[r];
            rowssq_p[idx] = rssq[r]; rowp2_p[idx]  = rp2[r];
        }
    }

    // negatives: full block reduce (negcnt = elements - possum)
    float negcnt = (float)(16 * CPB - possum);
#pragma unroll
    for (int m = 1; m <= 32; m <<= 1) {
        negsum += __shfl_xor(negsum, m, 64);
        negcnt += __shfl_xor(negcnt, m, 64);
    }
    if (lane == 0) { nred[wave][0] = negsum; nred[wave][1] = negcnt; }
    __syncthreads();
    if (tid == 0) {
        float ns = 0.f, nc = 0.f;
        for (int w = 0; w < 4; ++w) { ns += nred[w][0]; nc += nred[w][1]; }
        negs_p[bidx] = ns; negc_p[bidx] = nc;
    }
}

template <bool MAX>
__device__ inline float bred(float v, float* red)
{
#pragma unroll
    for (int m = 1; m <= 32; m <<= 1) {
        float o = __shfl_xor(v, m, 64);
        v = MAX ? fmaxf(v, o) : (v + o);
    }
    const int wave = threadIdx.x >> 6;
    const int lane = threadIdx.x & 63;
    if (lane == 0) red[wave] = v;
    __syncthreads();
    if (threadIdx.x == 0) {
        float r = red[0];
        for (int w = 1; w < 8; ++w) r = MAX ? fmaxf(r, red[w]) : (r + red[w]);
        red[8] = r;
    }
    __syncthreads();
    float out = red[8];
    __syncthreads();   // protect red[] before next reduction reuses it
    return out;
}

// grid (B, 2): y==0 -> column path (sharp1 + loss1), y==1 -> row path (loss2 + loss3)
__global__ __launch_bounds__(512)
void pass2_kernel(const float* __restrict__ ws, float* __restrict__ out)
{
    __shared__ float red[9];
    const int b = blockIdx.x;
    const int s = threadIdx.x;

    if (blockIdx.y == 0) {
        const float* colmax_p = ws + WS_COLMAX;
        const float* colsum_p = ws + WS_COLSUM;
        const float* colssq_p = ws + WS_COLSSQ;
        const float* colp1_p  = ws + WS_COLP1;

        float m = -3.4e38f, sm = 0.f, sq = 0.f, p1 = 0.f;
#pragma unroll
        for (int t = 0; t < TILES; ++t) {
            size_t idx = ((size_t)b * TILES + t) * S + s;
            m = fmaxf(m, colmax_p[idx]);
            sm += colsum_p[idx];
            sq += colssq_p[idx];
            p1 += colp1_p[idx];
        }
        float mean  = sm * (1.f / L);
        float var   = (sq - sm * sm * (1.f / L)) * (1.f / (L - 1));
        float score = (m - mean) / sqrtf(var);

        float gmax = bred<true>(score, red);
        float e    = __expf(score - gmax);
        float esum = bred<false>(e, red);
        float sharp1 = e / esum;
        out[(size_t)b * S + s] = sharp1;
        float loss1 = bred<false>(sharp1 * p1, red);
        if (s == 0) atomicAdd(out + (size_t)B * S, loss1 * (0.5f / B));
    } else {
        const float* rowmax_p = ws + WS_ROWMAX;
        const float* rowsum_p = ws + WS_ROWSUM;
        const float* rowssq_p = ws + WS_ROWSSQ;
        const float* rowp2_p  = ws + WS_ROWP2;
        const float* negs_p   = ws + WS_NEGS;
        const float* negc_p   = ws + WS_NEGC;

        size_t ridx = (size_t)b * L + s;
        float m2  = rowmax_p[ridx];
        float sm2 = rowsum_p[ridx];
        float sq2 = rowssq_p[ridx];
        float p2  = rowp2_p[ridx];

        float mean2  = sm2 * (1.f / S);
        float var2   = (sq2 - sm2 * sm2 * (1.f / S)) * (1.f / (S - 1));
        float score2 = (m2 - mean2) / sqrtf(var2);

        float gmax2 = bred<true>(score2, red);
        float e2    = __expf(score2 - gmax2);
        float esum2 = bred<false>(e2, red);
        float loss2 = bred<false>((e2 / esum2) * p2, red);

        if (s == 0) {
            float ns = 0.f, nc = 0.f;
            for (int t = 0; t < TILES; ++t) {
                ns += negs_p[b * TILES + t];
                nc += negc_p[b * TILES + t];
            }
            atomicAdd(out + (size_t)B * S, (0.5f * loss2 + ns / nc) * (1.f / B));
        }
    }
}

extern "C" void kernel_launch(void* const* d_in, const int* in_sizes, int n_in,
                              void* d_out, int out_size, void* d_ws, size_t ws_size,
                              hipStream_t stream)
{
    const float* q      = (const float*)d_in[0];
    const float* k      = (const float*)d_in[1];
    const int*   labels = (const int*)d_in[2];
    float* out = (float*)d_out;
    float* ws  = (float*)d_ws;

    pass1_kernel<<<dim3(B * TILES), dim3(256), 0, stream>>>(q, k, labels, ws, out);
    pass2_kernel<<<dim3(B, 2), dim3(512), 0, stream>>>(ws, out);
}

// Round 12
// 236.420 us; speedup vs baseline: 2.8244x; 1.0533x over previous
//
#include <hip/hip_runtime.h>

#define EPSF 1e-6f
#define LN2F 0.69314718055994531f

typedef _Float16 half8 __attribute__((ext_vector_type(8)));
typedef float f32x4 __attribute__((ext_vector_type(4)));

constexpr int B = 128, L = 512, S = 512, C = 64;
constexpr int TILE_R = 64;            // rows per pass-1 block
constexpr int TILES  = L / TILE_R;    // 8
constexpr int CHUNK  = 64;            // cols per k-chunk
constexpr int NCHUNK = S / CHUNK;     // 8
constexpr int HALVES = 2;             // S-split: each block does NCHUNK/HALVES chunks
constexpr int CPB    = NCHUNK / HALVES;   // 4 chunks per block

// workspace float offsets (row stats are per-half partials)
constexpr size_t WS_COLMAX = 0;
constexpr size_t WS_COLSUM = WS_COLMAX + (size_t)B * TILES * S;
constexpr size_t WS_COLSSQ = WS_COLSUM + (size_t)B * TILES * S;
constexpr size_t WS_COLP1  = WS_COLSSQ + (size_t)B * TILES * S;
constexpr size_t WS_ROWMAX = WS_COLP1  + (size_t)B * TILES * S;
constexpr size_t WS_ROWSUM = WS_ROWMAX + (size_t)B * L * HALVES;
constexpr size_t WS_ROWSSQ = WS_ROWSUM + (size_t)B * L * HALVES;
constexpr size_t WS_ROWP2  = WS_ROWSSQ + (size_t)B * L * HALVES;
constexpr size_t WS_NEGS   = WS_ROWP2  + (size_t)B * L * HALVES;
constexpr size_t WS_NEGC   = WS_NEGS   + (size_t)B * TILES * HALVES;

// Load a thread's 16 consecutive floats of a 64x64 tile: row = t>>2, c0 = (t&3)*16.
__device__ inline void loadTile(const float* __restrict__ g, float4 v[4], int t)
{
    const float* src = g + (t >> 2) * 64 + (t & 3) * 16;
    v[0] = *(const float4*)(src);
    v[1] = *(const float4*)(src + 4);
    v[2] = *(const float4*)(src + 8);
    v[3] = *(const float4*)(src + 12);
}

// Write regs into frag-swizzled fp16 hi/lo LDS:
// arr[(row>>4)*2 + (c>>5)][(((c>>3)&3)<<4) + (row&15)][c&7] -> fragment read is
// one lane-linear ds_read_b128. (R9: bank swizzle removes the 3.9M conflict
// cycles but buys 0 time — hidden under latency — and its +2 VGPR caused mild
// spill. R11: HALVES=1 also neutral-to-worse. Both reverted; R7 is the floor.)
__device__ inline void stageW(const float4 v4[4], half8 (*hiA)[64], half8 (*loA)[64], int t)
{
    const int row = t >> 2, c0 = (t & 3) * 16;
    const float v[16] = {v4[0].x, v4[0].y, v4[0].z, v4[0].w, v4[1].x, v4[1].y, v4[1].z, v4[1].w,
                         v4[2].x, v4[2].y, v4[2].z, v4[2].w, v4[3].x, v4[3].y, v4[3].z, v4[3].w};
#pragma unroll
    for (int o = 0; o < 2; ++o) {
        const int cb     = c0 + o * 8;
        const int idx    = (row >> 4) * 2 + (cb >> 5);
        const int lane_s = (((cb >> 3) & 3) << 4) + (row & 15);
        half8 h, l;
#pragma unroll
        for (int j = 0; j < 8; ++j) {
            float f = v[o * 8 + j];
            _Float16 hi = (_Float16)f;
            h[j] = hi;
            l[j] = (_Float16)(f - (float)hi);
        }
        hiA[idx][lane_s] = h;
        loA[idx][lane_s] = l;
    }
}

// R7 CHAMPION (236.5us, best of session). Exact R0 structure (VGPR 84, no
// spill) + three pressure-neutral edits: (1) scalar-loss slot zeroed here
// (memset dispatch dropped), (2) log2-domain NLL with one -ln2 scale per
// accumulator + negsum derived per-thread, (3) nontemporal label loads.
__global__ __launch_bounds__(256) __attribute__((amdgpu_waves_per_eu(3, 8)))
void pass1_kernel(const float* __restrict__ q, const float* __restrict__ kmat,
                  const int* __restrict__ labels, float* __restrict__ ws,
                  float* __restrict__ outp)
{
    __shared__ half8 khiF[8][64], kloF[8][64];   // 16 KB: frag-swizzled k (q in prologue)
    __shared__ float4 colred4[4][CHUNK];         // 4 KB (shuffle-reduced partials)
    __shared__ float nred[4][2];

    const int bidx = blockIdx.x;
    const int b    = bidx / (TILES * HALVES);
    const int rem  = bidx % (TILES * HALVES);
    const int tile = rem >> 1;
    const int half = rem & 1;
    const int chbase = half * CPB;
    const int tid  = threadIdx.x;
    const int lane = tid & 63;
    const int wave = tid >> 6;
    const int l15  = lane & 15;
    const int quad = lane >> 4;
    const int rowbase = tile * TILE_R;

    if (bidx == 0 && tid == 0) outp[(size_t)B * S] = 0.f;   // replaces memset dispatch

    float* colmax_p = ws + WS_COLMAX;
    float* colsum_p = ws + WS_COLSUM;
    float* colssq_p = ws + WS_COLSSQ;
    float* colp1_p  = ws + WS_COLP1;
    float* rowmax_p = ws + WS_ROWMAX;
    float* rowsum_p = ws + WS_ROWSUM;
    float* rowssq_p = ws + WS_ROWSSQ;
    float* rowp2_p  = ws + WS_ROWP2;
    float* negs_p   = ws + WS_NEGS;
    float* negc_p   = ws + WS_NEGC;

    const float* kb = kmat + (size_t)b * S * C;
    const int*   lb = labels + ((size_t)b * L + rowbase) * S;

    // --- prologue: q -> frag-swizzled LDS -> A fragments in registers ---
    float4 tv[4];
    loadTile(q + ((size_t)b * L + rowbase) * C, tv, tid);
    stageW(tv, khiF, kloF, tid);
    // labels for first chunk (consumed in first epilogue; reloaded after each)
    int labn[16];
#pragma unroll
    for (int ct = 0; ct < 4; ++ct)
#pragma unroll
        for (int r = 0; r < 4; ++r)
            labn[ct * 4 + r] = __builtin_nontemporal_load(
                &lb[(size_t)(wave * 16 + quad * 4 + r) * S
                    + chbase * CHUNK + ct * 16 + l15]);
    __syncthreads();   // publish q staging before fragment reads
    half8 ah0 = khiF[wave * 2 + 0][lane], ah1 = khiF[wave * 2 + 1][lane];
    half8 al0 = kloF[wave * 2 + 0][lane], al1 = kloF[wave * 2 + 1][lane];
    // prefetch first k chunk into registers (khiF not overwritten until after S1)
    loadTile(kb + (size_t)chbase * CHUNK * C, tv, tid);

    float rmax[4], rsum[4], rssq[4], rp2[4];
#pragma unroll
    for (int i = 0; i < 4; ++i) { rmax[i] = -3.4e38f; rsum[i] = 0.f; rssq[i] = 0.f; rp2[i] = 0.f; }
    float nlsum = 0.f;   // sum of log2(t) over ALL elements (negative)
    int   possum = 0;

    for (int c4 = 0; c4 < CPB; ++c4) {
        const int ch = chbase + c4;
        __syncthreads();   // S1: prev chunk's khiF frag reads + colred writes complete
        // combine + store column partials of previous chunk (reads colred4)
        if (c4 > 0 && tid < CHUNK) {
            float4 v = colred4[0][tid];
            float m0 = v.x, s1 = v.y, s2 = v.z, pp = v.w;
#pragma unroll
            for (int w = 1; w < 4; ++w) {
                float4 u = colred4[w][tid];
                m0 = fmaxf(m0, u.x); s1 += u.y; s2 += u.z; pp += u.w;
            }
            size_t idx = ((size_t)b * TILES + tile) * S + (ch - 1) * CHUNK + tid;
            colmax_p[idx] = m0; colsum_p[idx] = s1; colssq_p[idx] = s2; colp1_p[idx] = pp;
        }
        stageW(tv, khiF, kloF, tid);           // convert + write k(ch)
        if (c4 + 1 < CPB)
            loadTile(kb + (size_t)(ch + 1) * CHUNK * C, tv, tid);   // prefetch k(ch+1)
        __syncthreads();   // S2: k(ch) visible; colred4 reads done before re-write

        f32x4 acc[4];
#pragma unroll
        for (int ct = 0; ct < 4; ++ct) {
            half8 bh0 = khiF[ct * 2 + 0][lane], bh1 = khiF[ct * 2 + 1][lane];
            half8 bl0 = kloF[ct * 2 + 0][lane], bl1 = kloF[ct * 2 + 1][lane];
            f32x4 a = {0.f, 0.f, 0.f, 0.f};
            a = __builtin_amdgcn_mfma_f32_16x16x32_f16(ah0, bh0, a, 0, 0, 0);
            a = __builtin_amdgcn_mfma_f32_16x16x32_f16(ah0, bl0, a, 0, 0, 0);
            a = __builtin_amdgcn_mfma_f32_16x16x32_f16(al0, bh0, a, 0, 0, 0);
            a = __builtin_amdgcn_mfma_f32_16x16x32_f16(ah1, bh1, a, 0, 0, 0);
            a = __builtin_amdgcn_mfma_f32_16x16x32_f16(ah1, bl1, a, 0, 0, 0);
            a = __builtin_amdgcn_mfma_f32_16x16x32_f16(al1, bh1, a, 0, 0, 0);
            acc[ct] = a;
        }

        // epilogue: C/D layout col = l15, row = quad*4 + r  [m89-verified]
        // log2-domain NLL: accumulate raw log2, scale by -ln2 once at the end.
#pragma unroll
        for (int ct = 0; ct < 4; ++ct) {
            float cmax = -3.4e38f, csum = 0.f, cssq = 0.f, cp1 = 0.f;
#pragma unroll
            for (int r = 0; r < 4; ++r) {
                int lab = labn[ct * 4 + r];
                float sim = fmaf(0.5f, acc[ct][r], 0.5f);
                rmax[r] = fmaxf(rmax[r], sim);
                rsum[r] += sim;
                rssq[r] = fmaf(sim, sim, rssq[r]);
                cmax = fmaxf(cmax, sim);
                csum += sim;
                cssq = fmaf(sim, sim, cssq);
                bool  isp = (lab == 1);
                float tt  = isp ? sim : (1.f - sim);
                tt = fminf(fmaxf(tt, EPSF), 1.f - EPSF);
                float l2 = __log2f(tt);          // negative
                float pv = isp ? l2 : 0.f;
                rp2[r] += pv;                    // log2-domain pos-NLL
                cp1   += pv;
                nlsum += l2;                     // all elements
                possum += lab;
            }
            cp1 *= -LN2F;                        // natural-log positive NLL
            // column reduce across quads (lanes sharing l15): xor 16, 32
#pragma unroll
            for (int m = 16; m <= 32; m <<= 1) {
                cmax = fmaxf(cmax, __shfl_xor(cmax, m, 64));
                csum += __shfl_xor(csum, m, 64);
                cssq += __shfl_xor(cssq, m, 64);
                cp1  += __shfl_xor(cp1,  m, 64);
            }
            if (lane < 16)
                colred4[wave][ct * 16 + l15] = make_float4(cmax, csum, cssq, cp1);
        }

        // prefetch next chunk's labels AFTER consumption (cover: next S1/S2 +
        // staging + MFMA of chunk ch+1)
        if (c4 + 1 < CPB) {
#pragma unroll
            for (int ct = 0; ct < 4; ++ct)
#pragma unroll
                for (int r = 0; r < 4; ++r)
                    labn[ct * 4 + r] = __builtin_nontemporal_load(
                        &lb[(size_t)(wave * 16 + quad * 4 + r) * S
                            + (ch + 1) * CHUNK + ct * 16 + l15]);
        }
    }

    __syncthreads();
    if (tid < CHUNK) {   // last chunk's column partials
        float4 v = colred4[0][tid];
        float m0 = v.x, s1 = v.y, s2 = v.z, pp = v.w;
#pragma unroll
        for (int w = 1; w < 4; ++w) {
            float4 u = colred4[w][tid];
            m0 = fmaxf(m0, u.x); s1 += u.y; s2 += u.z; pp += u.w;
        }
        size_t idx = ((size_t)b * TILES + tile) * S + (chbase + CPB - 1) * CHUNK + tid;
        colmax_p[idx] = m0; colsum_p[idx] = s1; colssq_p[idx] = s2; colp1_p[idx] = pp;
    }

    // scale pos-NLL accumulators to natural log; derive this thread's negsum
    // BEFORE the row shuffles consume rp2
#pragma unroll
    for (int r = 0; r < 4; ++r) rp2[r] *= -LN2F;
    float negsum = fmaf(-LN2F, nlsum, -(rp2[0] + rp2[1] + rp2[2] + rp2[3]));

    // row reduce across l15 (lanes sharing quad): xor 1,2,4,8 -> per-half partial
#pragma unroll
    for (int r = 0; r < 4; ++r) {
#pragma unroll
        for (int m = 1; m <= 8; m <<= 1) {
            rmax[r] = fmaxf(rmax[r], __shfl_xor(rmax[r], m, 64));
            rsum[r] += __shfl_xor(rsum[r], m, 64);
            rssq[r] += __shfl_xor(rssq[r], m, 64);
            rp2[r]  += __shfl_xor(rp2[r],  m, 64);
        }
    }
    if (l15 == 0) {
#pragma unroll
        for (int r = 0; r < 4; ++r) {
            size_t idx = ((size_t)b * L + rowbase + wave * 16 + quad * 4 + r) * HALVES + half;
            rowmax_p[idx] = rmax[r]; rowsum_p[idx] = rsum[r];
            rowssq_p[idx] = rssq[r]; rowp2_p[idx]  = rp2[r];
        }
    }

    // negatives: full block reduce (negcnt = elements - possum)
    float negcnt = (float)(16 * CPB - possum);
#pragma unroll
    for (int m = 1; m <= 32; m <<= 1) {
        negsum += __shfl_xor(negsum, m, 64);
        negcnt += __shfl_xor(negcnt, m, 64);
    }
    if (lane == 0) { nred[wave][0] = negsum; nred[wave][1] = negcnt; }
    __syncthreads();
    if (tid == 0) {
        float ns = 0.f, nc = 0.f;
        for (int w = 0; w < 4; ++w) { ns += nred[w][0]; nc += nred[w][1]; }
        negs_p[bidx] = ns; negc_p[bidx] = nc;
    }
}

template <bool MAX>
__device__ inline float bred(float v, float* red)
{
#pragma unroll
    for (int m = 1; m <= 32; m <<= 1) {
        float o = __shfl_xor(v, m, 64);
        v = MAX ? fmaxf(v, o) : (v + o);
    }
    const int wave = threadIdx.x >> 6;
    const int lane = threadIdx.x & 63;
    if (lane == 0) red[wave] = v;
    __syncthreads();
    if (threadIdx.x == 0) {
        float r = red[0];
        for (int w = 1; w < 8; ++w) r = MAX ? fmaxf(r, red[w]) : (r + red[w]);
        red[8] = r;
    }
    __syncthreads();
    float out = red[8];
    __syncthreads();   // protect red[] before next reduction reuses it
    return out;
}

// grid (B, 2): y==0 -> column path (sharp1 + loss1), y==1 -> row path (loss2 + loss3)
__global__ __launch_bounds__(512)
void pass2_kernel(const float* __restrict__ ws, float* __restrict__ out)
{
    __shared__ float red[9];
    const int b = blockIdx.x;
    const int s = threadIdx.x;

    if (blockIdx.y == 0) {
        const float* colmax_p = ws + WS_COLMAX;
        const float* colsum_p = ws + WS_COLSUM;
        const float* colssq_p = ws + WS_COLSSQ;
        const float* colp1_p  = ws + WS_COLP1;

        float m = -3.4e38f, sm = 0.f, sq = 0.f, p1 = 0.f;
#pragma unroll
        for (int t = 0; t < TILES; ++t) {
            size_t idx = ((size_t)b * TILES + t) * S + s;
            m = fmaxf(m, colmax_p[idx]);
            sm += colsum_p[idx];
            sq += colssq_p[idx];
            p1 += colp1_p[idx];
        }
        float mean  = sm * (1.f / L);
        float var   = (sq - sm * sm * (1.f / L)) * (1.f / (L - 1));
        float score = (m - mean) / sqrtf(var);

        float gmax = bred<true>(score, red);
        float e    = __expf(score - gmax);
        float esum = bred<false>(e, red);
        float sharp1 = e / esum;
        out[(size_t)b * S + s] = sharp1;
        float loss1 = bred<false>(sharp1 * p1, red);
        if (s == 0) atomicAdd(out + (size_t)B * S, loss1 * (0.5f / B));
    } else {
        const float* rowmax_p = ws + WS_ROWMAX;
        const float* rowsum_p = ws + WS_ROWSUM;
        const float* rowssq_p = ws + WS_ROWSSQ;
        const float* rowp2_p  = ws + WS_ROWP2;
        const float* negs_p   = ws + WS_NEGS;
        const float* negc_p   = ws + WS_NEGC;

        size_t ridx = ((size_t)b * L + s) * HALVES;
        float m2 = rowmax_p[ridx], sm2 = rowsum_p[ridx];
        float sq2 = rowssq_p[ridx], p2 = rowp2_p[ridx];
#pragma unroll
        for (int h = 1; h < HALVES; ++h) {
            m2 = fmaxf(m2, rowmax_p[ridx + h]);
            sm2 += rowsum_p[ridx + h];
            sq2 += rowssq_p[ridx + h];
            p2  += rowp2_p[ridx + h];
        }
        float mean2  = sm2 * (1.f / S);
        float var2   = (sq2 - sm2 * sm2 * (1.f / S)) * (1.f / (S - 1));
        float score2 = (m2 - mean2) / sqrtf(var2);

        float gmax2 = bred<true>(score2, red);
        float e2    = __expf(score2 - gmax2);
        float esum2 = bred<false>(e2, red);
        float loss2 = bred<false>((e2 / esum2) * p2, red);

        if (s == 0) {
            float ns = 0.f, nc = 0.f;
            for (int t = 0; t < TILES * HALVES; ++t) {
                ns += negs_p[b * TILES * HALVES + t];
                nc += negc_p[b * TILES * HALVES + t];
            }
            atomicAdd(out + (size_t)B * S, (0.5f * loss2 + ns / nc) * (1.f / B));
        }
    }
}

extern "C" void kernel_launch(void* const* d_in, const int* in_sizes, int n_in,
                              void* d_out, int out_size, void* d_ws, size_t ws_size,
                              hipStream_t stream)
{
    const float* q      = (const float*)d_in[0];
    const float* k      = (const float*)d_in[1];
    const int*   labels = (const int*)d_in[2];
    float* out = (float*)d_out;
    float* ws  = (float*)d_ws;

    pass1_kernel<<<dim3(B * TILES * HALVES), dim3(256), 0, stream>>>(q, k, labels, ws, out);
    pass2_kernel<<<dim3(B, 2), dim3(512), 0, stream>>>(ws, out);
}